// Round 2
// baseline (357.765 us; speedup 1.0000x reference)
//
#include <hip/hip_runtime.h>
#include <hip/hip_bf16.h>

// Problem constants
#define B_     16384
#define TD     512     // T*D
#define HID    128
#define LAT    512     // N_TOKENS*CODE_DIM
#define NCODES 512
#define CDIM   64
#define NTOK   8
#define EPS    1e-5f

// ---------------------------------------------------------------------------
// c2[c] = sum_d codebook[c][d]^2   (one wave per code)
// ---------------------------------------------------------------------------
__global__ void c2_kernel(const float* __restrict__ cb, float* __restrict__ c2) {
    int c = blockIdx.x;
    int d = threadIdx.x;            // 64 threads = 1 wave
    float v = cb[c * CDIM + d];
    float s = v * v;
#pragma unroll
    for (int m = 32; m >= 1; m >>= 1) s += __shfl_xor(s, m, 64);
    if (d == 0) c2[c] = s;
}

// ---------------------------------------------------------------------------
// Tiled fp32 GEMM: C[M,N] = A[M,K] @ W[K,N] + bias, optional ReLU / LayerNorm
// (LN over groups of 64 output cols == one token). fp32 output always.
// BM=64, BN=64, BK=32, 256 threads, 4x4 microtile.
// ---------------------------------------------------------------------------
template<bool RELU, bool LN>
__launch_bounds__(256)
__global__ void gemm_kernel(const float* __restrict__ A, const float* __restrict__ W,
                            const float* __restrict__ bias,
                            float* __restrict__ C,
                            int M, int N, int K) {
    constexpr int BM = 64, BN = 64, BK = 32;
    __shared__ float As[BK][BM + 4];   // transposed: As[k][m]
    __shared__ float Ws[BK][BN + 4];

    const int tid = threadIdx.x;
    const int tx  = tid & 15;          // 0..15 (cols)
    const int ty  = tid >> 4;          // 0..15 (rows)
    const int m0  = blockIdx.x * BM;
    const int n0  = blockIdx.y * BN;

    float acc[4][4] = {};

    for (int k0 = 0; k0 < K; k0 += BK) {
        // A tile: 64 rows x 32 k, stored transposed
        {
            int r  = tid >> 3;               // 0..31
            int c4 = (tid & 7) * 4;          // 0..28
#pragma unroll
            for (int h = 0; h < 2; ++h) {
                int rr = r + h * 32;
                float4 v = *(const float4*)&A[(size_t)(m0 + rr) * K + k0 + c4];
                As[c4 + 0][rr] = v.x; As[c4 + 1][rr] = v.y;
                As[c4 + 2][rr] = v.z; As[c4 + 3][rr] = v.w;
            }
        }
        // W tile: 32 k x 64 n, direct
        {
            int r  = tid >> 4;               // 0..15
            int c4 = (tid & 15) * 4;         // 0..60
#pragma unroll
            for (int h = 0; h < 2; ++h) {
                int rr = r + h * 16;
                float4 v = *(const float4*)&W[(size_t)(k0 + rr) * N + n0 + c4];
                *(float4*)&Ws[rr][c4] = v;
            }
        }
        __syncthreads();

#pragma unroll
        for (int kk = 0; kk < BK; ++kk) {
            float4 a = *(const float4*)&As[kk][ty * 4];
            float4 b = *(const float4*)&Ws[kk][tx * 4];
            float av[4] = {a.x, a.y, a.z, a.w};
            float bv[4] = {b.x, b.y, b.z, b.w};
#pragma unroll
            for (int i = 0; i < 4; ++i)
#pragma unroll
                for (int j = 0; j < 4; ++j)
                    acc[i][j] = fmaf(av[i], bv[j], acc[i][j]);
        }
        __syncthreads();
    }

    // Epilogue
    float bv[4];
#pragma unroll
    for (int j = 0; j < 4; ++j) bv[j] = bias[n0 + tx * 4 + j];

#pragma unroll
    for (int i = 0; i < 4; ++i) {
        float c[4];
#pragma unroll
        for (int j = 0; j < 4; ++j) {
            c[j] = acc[i][j] + bv[j];
            if (RELU) c[j] = fmaxf(c[j], 0.0f);
        }
        if (LN) {
            // LN across the 64 cols of this row; the 16 tx lanes of one ty group
            // are lane-contiguous within a wave -> shfl_xor over masks 1,2,4,8.
            float s  = c[0] + c[1] + c[2] + c[3];
            float ss = c[0]*c[0] + c[1]*c[1] + c[2]*c[2] + c[3]*c[3];
#pragma unroll
            for (int m = 1; m <= 8; m <<= 1) {
                s  += __shfl_xor(s,  m, 64);
                ss += __shfl_xor(ss, m, 64);
            }
            float mean = s * (1.0f / 64.0f);
            float var  = ss * (1.0f / 64.0f) - mean * mean;
            float rstd = rsqrtf(var + EPS);
#pragma unroll
            for (int j = 0; j < 4; ++j) c[j] = (c[j] - mean) * rstd;
        }
        size_t row = (size_t)(m0 + ty * 4 + i);
        *(float4*)&C[row * N + n0 + tx * 4] = make_float4(c[0], c[1], c[2], c[3]);
    }
}

// ---------------------------------------------------------------------------
// VQ: per token (row of z_ln [Mt,64]) find argmin_c ||z - cb[c]||^2 via
// score = c2[c] - 2*dot(z, cb[c]). 64 tokens/block, codebook in 4 chunks of
// 128 codes staged in LDS. Writes z_q fp32 to ws (decoder input) AND to the
// z_q output chunk; indices as float to the idx output chunk.
// ---------------------------------------------------------------------------
__launch_bounds__(256)
__global__ void vq_kernel(const float* __restrict__ zln, const float* __restrict__ cb,
                          const float* __restrict__ c2, float* __restrict__ zq_ws,
                          float* __restrict__ zq_out, float* __restrict__ idx_out) {
    __shared__ float Zs[CDIM][64 + 4];     // transposed z tile: Zs[d][tok]
    __shared__ float CBs[CDIM][128 + 4];   // transposed codebook chunk: CBs[d][code]
    __shared__ float c2s[NCODES];

    const int tid = threadIdx.x;
    const int tx  = tid & 15;              // code groups
    const int ty  = tid >> 4;              // token groups
    const int m0  = blockIdx.x * 64;       // token base

    // stage z tile (transposed)
#pragma unroll
    for (int h = 0; h < 4; ++h) {
        int idx = tid + 256 * h;           // 0..1023
        int r   = idx >> 4;                // 0..63
        int d4  = (idx & 15) * 4;
        float4 v = *(const float4*)&zln[(size_t)(m0 + r) * CDIM + d4];
        Zs[d4 + 0][r] = v.x; Zs[d4 + 1][r] = v.y;
        Zs[d4 + 2][r] = v.z; Zs[d4 + 3][r] = v.w;
    }
    c2s[tid]       = c2[tid];
    c2s[tid + 256] = c2[tid + 256];

    float best[4];
    int   bidx[4];
#pragma unroll
    for (int i = 0; i < 4; ++i) { best[i] = 3.4e38f; bidx[i] = 0; }

    for (int c0 = 0; c0 < NCODES; c0 += 128) {
        __syncthreads();   // protect CBs reuse (and cover Zs/c2s on first pass)
#pragma unroll
        for (int h = 0; h < 8; ++h) {
            int idx = tid + 256 * h;       // 0..2047
            int c   = idx >> 4;            // 0..127
            int d4  = (idx & 15) * 4;
            float4 v = *(const float4*)&cb[(size_t)(c0 + c) * CDIM + d4];
            CBs[d4 + 0][c] = v.x; CBs[d4 + 1][c] = v.y;
            CBs[d4 + 2][c] = v.z; CBs[d4 + 3][c] = v.w;
        }
        __syncthreads();

        float cr[4][8] = {};
#pragma unroll 8
        for (int k = 0; k < CDIM; ++k) {
            float4 a  = *(const float4*)&Zs[k][ty * 4];
            float4 b0 = *(const float4*)&CBs[k][tx * 8];
            float4 b1 = *(const float4*)&CBs[k][tx * 8 + 4];
            float av[4] = {a.x, a.y, a.z, a.w};
            float bw[8] = {b0.x, b0.y, b0.z, b0.w, b1.x, b1.y, b1.z, b1.w};
#pragma unroll
            for (int i = 0; i < 4; ++i)
#pragma unroll
                for (int j = 0; j < 8; ++j)
                    cr[i][j] = fmaf(av[i], bw[j], cr[i][j]);
        }
#pragma unroll
        for (int i = 0; i < 4; ++i)
#pragma unroll
            for (int j = 0; j < 8; ++j) {
                int c = c0 + tx * 8 + j;
                float s = fmaf(-2.0f, cr[i][j], c2s[c]);
                // ascending c scan + strict < == numpy first-min tie-break
                if (s < best[i]) { best[i] = s; bidx[i] = c; }
            }
    }

    // reduce across the 16 tx lanes (lane-aligned group), tie-break to lower idx
#pragma unroll
    for (int i = 0; i < 4; ++i) {
        float s = best[i];
        int  bi = bidx[i];
#pragma unroll
        for (int m = 1; m <= 8; m <<= 1) {
            float so = __shfl_xor(s, m, 64);
            int   io = __shfl_xor(bi, m, 64);
            if (so < s || (so == s && io < bi)) { s = so; bi = io; }
        }
        int row = m0 + ty * 4 + i;
        // gather codebook[bi] cooperatively: lane tx covers dims tx*4..tx*4+3
        float4 q = *(const float4*)&cb[(size_t)bi * CDIM + tx * 4];
        *(float4*)&zq_ws [(size_t)row * CDIM + tx * 4] = q;  // ws (decoder input)
        *(float4*)&zq_out[(size_t)row * CDIM + tx * 4] = q;  // output chunk 1 (fp32)
        if (tx == 0) idx_out[row] = (float)bi;               // output chunk 2 (fp32)
    }
}

// ---------------------------------------------------------------------------
extern "C" void kernel_launch(void* const* d_in, const int* in_sizes, int n_in,
                              void* d_out, int out_size, void* d_ws, size_t ws_size,
                              hipStream_t stream) {
    const float* x      = (const float*)d_in[0];
    const float* enc_w1 = (const float*)d_in[1];
    const float* enc_b1 = (const float*)d_in[2];
    const float* enc_w2 = (const float*)d_in[3];
    const float* enc_b2 = (const float*)d_in[4];
    const float* cbk    = (const float*)d_in[5];
    const float* dec_w1 = (const float*)d_in[6];
    const float* dec_b1 = (const float*)d_in[7];
    const float* dec_w2 = (const float*)d_in[8];
    const float* dec_b2 = (const float*)d_in[9];

    // outputs, all float32, concatenated flat: recon | z_q | indices
    float* out     = (float*)d_out;
    float* recon_o = out;
    float* zq_o    = out + (size_t)B_ * TD;                 //  8,388,608
    float* idx_o   = out + 2 * (size_t)B_ * TD;             // 16,777,216

    // workspace: zbuf [B,512] f32 (z_e_ln then z_q), hbuf [B,128] f32, c2[512]
    float* zbuf  = (float*)d_ws;
    float* hbuf  = zbuf + (size_t)B_ * TD;
    float* c2buf = hbuf + (size_t)B_ * HID;

    hipLaunchKernelGGL(c2_kernel, dim3(NCODES), dim3(64), 0, stream, cbk, c2buf);

    // encoder GEMM1 + ReLU: [B,512] @ [512,128] -> hbuf
    hipLaunchKernelGGL((gemm_kernel<true, false>), dim3(B_ / 64, HID / 64), dim3(256), 0,
                       stream, x, enc_w1, enc_b1, hbuf, B_, HID, TD);

    // encoder GEMM2 + LN: [B,128] @ [128,512] -> zbuf (layer-normed per 64-dim token)
    hipLaunchKernelGGL((gemm_kernel<false, true>), dim3(B_ / 64, LAT / 64), dim3(256), 0,
                       stream, hbuf, enc_w2, enc_b2, zbuf, B_, LAT, HID);

    // VQ: argmin + gather; zbuf becomes z_q fp32; writes zq/idx fp32 outputs
    hipLaunchKernelGGL(vq_kernel, dim3(B_ * NTOK / 64), dim3(256), 0, stream,
                       zbuf, cbk, c2buf, zbuf, zq_o, idx_o);

    // decoder GEMM1 + ReLU: [B,512] @ [512,128] -> hbuf
    hipLaunchKernelGGL((gemm_kernel<true, false>), dim3(B_ / 64, HID / 64), dim3(256), 0,
                       stream, zbuf, dec_w1, dec_b1, hbuf, B_, HID, TD);

    // decoder GEMM2: [B,128] @ [128,512] -> recon fp32
    hipLaunchKernelGGL((gemm_kernel<false, false>), dim3(B_ / 64, TD / 64), dim3(256), 0,
                       stream, hbuf, dec_w2, dec_b2, recon_o, B_, TD, HID);
}